// Round 8
// baseline (222.177 us; speedup 1.0000x reference)
//
#include <hip/hip_runtime.h>
#include <hip/hip_bf16.h>
#include <stdint.h>

#define Bv 8
#define Nv 4096
#define Cv 256
#define Kv 16
#define RPEv 64
#define CAPv 160

typedef short bf16x8 __attribute__((ext_vector_type(8)));
typedef float f32x4 __attribute__((ext_vector_type(4)));
typedef _Float16 half2v __attribute__((ext_vector_type(2)));
typedef unsigned short u16x2 __attribute__((ext_vector_type(2)));

static __device__ __forceinline__ float bf2f(unsigned int u16) {
    union { unsigned int i; float f; } v; v.i = u16 << 16; return v.f;
}
static __device__ __forceinline__ unsigned short f2bf(float f) {
    union { float f; unsigned int i; } v; v.f = f;
    unsigned int x = v.i;
    return (unsigned short)((x + 0x7fffu + ((x >> 16) & 1u)) >> 16);
}
static __device__ __forceinline__ unsigned int umin32(unsigned int a, unsigned int b) { return a < b ? a : b; }
static __device__ __forceinline__ unsigned int umax32(unsigned int a, unsigned int b) { return a > b ? a : b; }
static __device__ __forceinline__ unsigned short f2h(float f) {
    _Float16 h = (_Float16)f; return __builtin_bit_cast(unsigned short, h);
}
static __device__ __forceinline__ float h2f(unsigned int u) {
    _Float16 h = __builtin_bit_cast(_Float16, (unsigned short)(u & 0xffffu)); return (float)h;
}
static __device__ __forceinline__ half2v bch2(unsigned int u) { return __builtin_bit_cast(half2v, u); }
static __device__ __forceinline__ unsigned int bcu32(u16x2 v) { return __builtin_bit_cast(unsigned int, v); }

// ---------------- K0: fused preamble -----------------------------------
// blocks 0-4095: dual LayerNorm + bf16 cast; 4096-5119: weight transpose;
// 5120: w2sum/b2sum prep. All independent.
__global__ __launch_bounds__(256) void pre_kernel(
    const float* __restrict__ x,
    const float* __restrict__ gq, const float* __restrict__ bq,
    const float* __restrict__ gkv, const float* __restrict__ bkv,
    unsigned short* __restrict__ Aq, unsigned short* __restrict__ Akv,
    const float* __restrict__ Wq, const float* __restrict__ Wk,
    const float* __restrict__ Wv, const float* __restrict__ Wp,
    unsigned short* __restrict__ Bt,
    const float* __restrict__ W2, const float* __restrict__ b2,
    float* __restrict__ w2sum, float* __restrict__ b2sum)
{
    const int bid = blockIdx.x;
    const int tid = threadIdx.x;
    if (bid < 4096) {
        // ---- dual LayerNorm + bf16 cast ----
        const long r0 = (long)bid * 8;
        const int row = tid >> 5;
        const int c0 = (tid & 31) * 8;
        const float* xr = x + (r0 + row) * Cv + c0;
        float xv[8];
        *(float4*)&xv[0] = *(const float4*)xr;
        *(float4*)&xv[4] = *(const float4*)(xr + 4);
        float s = 0.f, s2 = 0.f;
#pragma unroll
        for (int i = 0; i < 8; ++i) { s += xv[i]; s2 = fmaf(xv[i], xv[i], s2); }
#pragma unroll
        for (int m = 16; m >= 1; m >>= 1) { s += __shfl_xor(s, m); s2 += __shfl_xor(s2, m); }
        const float mean = s * (1.f / Cv);
        const float var = fmaf(-mean, mean, s2 * (1.f / Cv));
        const float rs = rsqrtf(fmaxf(var, 0.f) + 1e-5f);
        unsigned int pq[4], pk[4];
#pragma unroll
        for (int i = 0; i < 4; ++i) {
            const int c = c0 + 2 * i;
            const float h0 = (xv[2 * i] - mean) * rs;
            const float h1 = (xv[2 * i + 1] - mean) * rs;
            const unsigned int q0 = f2bf(fmaf(h0, gq[c], bq[c]));
            const unsigned int q1 = f2bf(fmaf(h1, gq[c + 1], bq[c + 1]));
            const unsigned int k0 = f2bf(fmaf(h0, gkv[c], bkv[c]));
            const unsigned int k1 = f2bf(fmaf(h1, gkv[c + 1], bkv[c + 1]));
            pq[i] = q0 | (q1 << 16);
            pk[i] = k0 | (k1 << 16);
        }
        const long off = (r0 + row) * Cv + c0;
        *(uint4*)&Aq[off]  = make_uint4(pq[0], pq[1], pq[2], pq[3]);
        *(uint4*)&Akv[off] = make_uint4(pk[0], pk[1], pk[2], pk[3]);
    } else if (bid < 5120) {
        // ---- weight transpose-cast: Bt[1024][256] ----
        const int r = bid - 4096;
        const float* W = (r < 256) ? Wq : (r < 512) ? Wk : (r < 768) ? Wv : Wp;
        const int n = r & 255;
        Bt[r * 256 + tid] = f2bf(W[tid * 256 + n]);
    } else {
        // ---- w2sum / b2sum ----
        if (tid < RPEv) {
            float s = 0.f;
            for (int c = 0; c < Cv; ++c) s += W2[tid * Cv + c];
            w2sum[tid] = s;
        }
        if (tid == 0) {
            float s = 0.f;
            for (int c = 0; c < Cv; ++c) s += b2[c];
            *b2sum = s;
        }
    }
}

// ---------------- K1b: bf16 MFMA GEMM  C[32768 x 768] = A @ W (bf16 out) ---
__global__ __launch_bounds__(256) void gemm_qkv_kernel(
    const unsigned short* __restrict__ Aq, const unsigned short* __restrict__ Akv,
    const unsigned short* __restrict__ Bt,
    unsigned short* __restrict__ qo, unsigned short* __restrict__ ko,
    unsigned short* __restrict__ vo)
{
    __shared__ unsigned short Albs[2][128 * 64];
    __shared__ unsigned short Blbs[2][128 * 64];

    const int tid = threadIdx.x;
    const int rt = blockIdx.x;          // row tile: 256
    const int ct = blockIdx.y;          // col tile: 6
    const unsigned short* A = (ct < 2) ? Aq : Akv;
    const int mat = ct >> 1;
    unsigned short* outp = (mat == 0) ? qo : (mat == 1) ? ko : vo;
    const int colInMat = (ct & 1) * 128;

    const int wid = tid >> 6, l = tid & 63;
    const int wr = wid >> 1, wc = wid & 1;

    int srow[4], scol8[4];
#pragma unroll
    for (int it = 0; it < 4; ++it) {
        const int chunk = it * 256 + tid;
        srow[it] = chunk >> 3;
        scol8[it] = ((chunk & 7) ^ (srow[it] & 7)) * 8;
    }

#define STAGE(buf, ks)                                                                  \
    {                                                                                   \
        _Pragma("unroll")                                                               \
        for (int it = 0; it < 4; ++it) {                                                \
            const unsigned short* ga = A + ((size_t)(rt * 128 + srow[it])) * 256        \
                                         + (ks) * 64 + scol8[it];                       \
            const unsigned short* gb = Bt + ((size_t)(ct * 128 + srow[it])) * 256       \
                                          + (ks) * 64 + scol8[it];                      \
            __builtin_amdgcn_global_load_lds(                                           \
                (const __attribute__((address_space(1))) unsigned int*)(const void*)ga, \
                (__attribute__((address_space(3))) unsigned int*)(void*)                \
                    ((char*)&Albs[buf][0] + (it * 256 + tid) * 16), 16, 0, 0);          \
            __builtin_amdgcn_global_load_lds(                                           \
                (const __attribute__((address_space(1))) unsigned int*)(const void*)gb, \
                (__attribute__((address_space(3))) unsigned int*)(void*)                \
                    ((char*)&Blbs[buf][0] + (it * 256 + tid) * 16), 16, 0, 0);          \
        }                                                                               \
    }

    f32x4 acc[4][4];
#pragma unroll
    for (int m = 0; m < 4; ++m)
#pragma unroll
        for (int n = 0; n < 4; ++n) acc[m][n] = (f32x4){0.f, 0.f, 0.f, 0.f};

    STAGE(0, 0);
    __syncthreads();

    for (int ks = 0; ks < 4; ++ks) {
        const int cur = ks & 1;
        if (ks < 3) STAGE(cur ^ 1, ks + 1);
#pragma unroll
        for (int kk = 0; kk < 2; ++kk) {
            bf16x8 a[4], b[4];
#pragma unroll
            for (int m = 0; m < 4; ++m) {
                const int row = wr * 64 + m * 16 + (l & 15);
                const int byte = row * 128 + ((((kk * 4 + (l >> 4)) * 16)) ^ ((row & 7) << 4));
                a[m] = *(const bf16x8*)((const char*)&Albs[cur][0] + byte);
            }
#pragma unroll
            for (int n = 0; n < 4; ++n) {
                const int row = wc * 64 + n * 16 + (l & 15);
                const int byte = row * 128 + ((((kk * 4 + (l >> 4)) * 16)) ^ ((row & 7) << 4));
                b[n] = *(const bf16x8*)((const char*)&Blbs[cur][0] + byte);
            }
#pragma unroll
            for (int m = 0; m < 4; ++m)
#pragma unroll
                for (int n = 0; n < 4; ++n)
                    acc[m][n] = __builtin_amdgcn_mfma_f32_16x16x32_bf16(a[m], b[n], acc[m][n], 0, 0, 0);
        }
        __syncthreads();
    }

#pragma unroll
    for (int m = 0; m < 4; ++m) {
#pragma unroll
        for (int n = 0; n < 4; ++n) {
#pragma unroll
            for (int j = 0; j < 4; ++j) {
                const int row = rt * 128 + wr * 64 + m * 16 + (l >> 4) * 4 + j;
                const int col = colInMat + wc * 64 + n * 16 + (l & 15);
                outp[(size_t)row * 256 + col] = f2bf(acc[m][n][j]);
            }
        }
    }
#undef STAGE
}

// ---------------- K4: proj GEMM  out[32768 x 256] = o @ Wp^T + bp (f32) ----
__global__ __launch_bounds__(256) void gemm_proj_kernel(
    const unsigned short* __restrict__ Ab, const unsigned short* __restrict__ Btp,
    const float* __restrict__ bp, float* __restrict__ out)
{
    __shared__ unsigned short Albs[2][128 * 64];
    __shared__ unsigned short Blbs[2][128 * 64];

    const int tid = threadIdx.x;
    const int rt = blockIdx.x;          // 256
    const int ct = blockIdx.y;          // 2

    const int wid = tid >> 6, l = tid & 63;
    const int wr = wid >> 1, wc = wid & 1;

    int srow[4], scol8[4];
#pragma unroll
    for (int it = 0; it < 4; ++it) {
        const int chunk = it * 256 + tid;
        srow[it] = chunk >> 3;
        scol8[it] = ((chunk & 7) ^ (srow[it] & 7)) * 8;
    }

#define STAGE(buf, ks)                                                                  \
    {                                                                                   \
        _Pragma("unroll")                                                               \
        for (int it = 0; it < 4; ++it) {                                                \
            const unsigned short* ga = Ab + ((size_t)(rt * 128 + srow[it])) * 256       \
                                          + (ks) * 64 + scol8[it];                      \
            const unsigned short* gb = Btp + ((size_t)(ct * 128 + srow[it])) * 256      \
                                           + (ks) * 64 + scol8[it];                     \
            __builtin_amdgcn_global_load_lds(                                           \
                (const __attribute__((address_space(1))) unsigned int*)(const void*)ga, \
                (__attribute__((address_space(3))) unsigned int*)(void*)                \
                    ((char*)&Albs[buf][0] + (it * 256 + tid) * 16), 16, 0, 0);          \
            __builtin_amdgcn_global_load_lds(                                           \
                (const __attribute__((address_space(1))) unsigned int*)(const void*)gb, \
                (__attribute__((address_space(3))) unsigned int*)(void*)                \
                    ((char*)&Blbs[buf][0] + (it * 256 + tid) * 16), 16, 0, 0);          \
        }                                                                               \
    }

    f32x4 acc[4][4];
#pragma unroll
    for (int m = 0; m < 4; ++m)
#pragma unroll
        for (int n = 0; n < 4; ++n) acc[m][n] = (f32x4){0.f, 0.f, 0.f, 0.f};

    STAGE(0, 0);
    __syncthreads();

    for (int ks = 0; ks < 4; ++ks) {
        const int cur = ks & 1;
        if (ks < 3) STAGE(cur ^ 1, ks + 1);
#pragma unroll
        for (int kk = 0; kk < 2; ++kk) {
            bf16x8 a[4], b[4];
#pragma unroll
            for (int m = 0; m < 4; ++m) {
                const int row = wr * 64 + m * 16 + (l & 15);
                const int byte = row * 128 + ((((kk * 4 + (l >> 4)) * 16)) ^ ((row & 7) << 4));
                a[m] = *(const bf16x8*)((const char*)&Albs[cur][0] + byte);
            }
#pragma unroll
            for (int n = 0; n < 4; ++n) {
                const int row = wc * 64 + n * 16 + (l & 15);
                const int byte = row * 128 + ((((kk * 4 + (l >> 4)) * 16)) ^ ((row & 7) << 4));
                b[n] = *(const bf16x8*)((const char*)&Blbs[cur][0] + byte);
            }
#pragma unroll
            for (int m = 0; m < 4; ++m)
#pragma unroll
                for (int n = 0; n < 4; ++n)
                    acc[m][n] = __builtin_amdgcn_mfma_f32_16x16x32_bf16(a[m], b[n], acc[m][n], 0, 0, 0);
        }
        __syncthreads();
    }

#pragma unroll
    for (int n = 0; n < 4; ++n) {
        const int col = ct * 128 + wc * 64 + n * 16 + (l & 15);
        const float bpv = bp[col];
#pragma unroll
        for (int m = 0; m < 4; ++m) {
#pragma unroll
            for (int j = 0; j < 4; ++j) {
                const int row = rt * 128 + wr * 64 + m * 16 + (l >> 4) * 4 + j;
                out[(size_t)row * 256 + col] = acc[m][n][j] + bpv;
            }
        }
    }
#undef STAGE
}

// ---------------- K2: kNN v7 — half-sample pass A, split chains ------------
// Pass A: 8 thr/query over pairs p=16t+s (HALF sample; tau from any subset is
//         a valid >= d16 bound), two independent packed chain-3s (even/odd t)
//         merged at end -> 48-union; merge takes 16th smallest -> tau.
// Pass B: full scan, 8 packed reg-pairs/thread vs 32 queries, LDS append.
// Tail: exact f64 re-rank of survivors (bit-identical comparator).
__global__ __launch_bounds__(256) void knn_kernel(
    const float* __restrict__ pos, int* __restrict__ idx_out)
{
    __shared__ uint2 pxy2[Nv / 2];               // 16 KB fp16 (x0|x1, y0|y1)
    __shared__ unsigned int pz2[Nv / 2];         // 8 KB fp16 (z0|z1)
    __shared__ uint4 qu[32];                     // qx_pk, qy_pk, qz_pk, tau_u16
    __shared__ unsigned int akeys[256 * 3];      // 3 KB pass-A packed chains
    __shared__ unsigned int cnt[32];
    __shared__ unsigned short bufs[32 * CAPv];   // 10 KB survivor indices

    const int tid = threadIdx.x;
    const int ql = tid >> 3;                 // 0..31 query within block
    const int s  = tid & 7;                  // segment 0..7
    const int q  = blockIdx.x * 32 + ql;
    const int b  = q >> 12;
    const int n  = q & (Nv - 1);
    const float* pb = pos + (size_t)b * Nv * 3;

    for (int i = tid; i < Nv / 2; i += 256) {
        const float* pp = pb + 6 * i;
        const float2 u0 = *(const float2*)pp;
        const float2 u1 = *(const float2*)(pp + 2);
        const float2 u2 = *(const float2*)(pp + 4);
        const unsigned int x0 = f2h(u0.x), y0 = f2h(u0.y), z0 = f2h(u1.x);
        const unsigned int x1 = f2h(u1.y), y1 = f2h(u2.x), z1 = f2h(u2.y);
        pxy2[i] = make_uint2(x0 | (x1 << 16), y0 | (y1 << 16));
        pz2[i] = z0 | (z1 << 16);
    }
    __syncthreads();

    // query packed regs (broadcast fp16 into both halves)
    const int pq = n >> 1;
    const int hq = (n & 1) * 16;
    const uint2 qxy = pxy2[pq];
    const unsigned int qzz = pz2[pq];
    const unsigned int hx = (qxy.x >> hq) & 0xffffu;
    const unsigned int hy = (qxy.y >> hq) & 0xffffu;
    const unsigned int hz = (qzz   >> hq) & 0xffffu;
    const half2v qxp = bch2(hx | (hx << 16));
    const half2v qyp = bch2(hy | (hy << 16));
    const half2v qzp = bch2(hz | (hz << 16));

    // ---- Pass A: half-sample, split even/odd chains, p = 16t+s ----
    u16x2 a0 = {0x7c00, 0x7c00}, a1 = a0, a2 = a0;   // +inf fp16
    u16x2 e0 = a0, e1 = a0, e2 = a0;
#pragma unroll 4
    for (int t = 0; t < 128; ++t) {
        const int p = 16 * t + s;
        const uint2 xy = pxy2[p];
        const unsigned int zz = pz2[p];
        const half2v dx = bch2(xy.x) - qxp;
        const half2v dy = bch2(xy.y) - qyp;
        const half2v dz = bch2(zz) - qzp;
        const half2v d2 = dx * dx + dy * dy + dz * dz;
        const u16x2 k = __builtin_bit_cast(u16x2, d2);
        if (t & 1) {
            const u16x2 mn0 = __builtin_elementwise_min(e0, k);
            const u16x2 mx0 = __builtin_elementwise_max(e0, k);
            e0 = mn0;
            const u16x2 mn1 = __builtin_elementwise_min(e1, mx0);
            const u16x2 mx1 = __builtin_elementwise_max(e1, mx0);
            e1 = mn1;
            e2 = __builtin_elementwise_min(e2, mx1);
        } else {
            const u16x2 mn0 = __builtin_elementwise_min(a0, k);
            const u16x2 mx0 = __builtin_elementwise_max(a0, k);
            a0 = mn0;
            const u16x2 mn1 = __builtin_elementwise_min(a1, mx0);
            const u16x2 mx1 = __builtin_elementwise_max(a1, mx0);
            a1 = mn1;
            a2 = __builtin_elementwise_min(a2, mx1);
        }
    }
    // merge e-chain into a-chain (3 full inserts)
#pragma unroll
    for (int i = 0; i < 3; ++i) {
        const u16x2 k = (i == 0) ? e0 : (i == 1) ? e1 : e2;
        const u16x2 mn0 = __builtin_elementwise_min(a0, k);
        const u16x2 mx0 = __builtin_elementwise_max(a0, k);
        a0 = mn0;
        const u16x2 mn1 = __builtin_elementwise_min(a1, mx0);
        const u16x2 mx1 = __builtin_elementwise_max(a1, mx0);
        a1 = mn1;
        a2 = __builtin_elementwise_min(a2, mx1);
    }
    akeys[tid * 3 + 0] = bcu32(a0);
    akeys[tid * 3 + 1] = bcu32(a1);
    akeys[tid * 3 + 2] = bcu32(a2);
    __syncthreads();

    // ---- merge: 16th smallest of the 48-union -> tau ----
    if (tid < 32) {
        unsigned int sel16[16];
#pragma unroll
        for (int i = 0; i < 16; ++i) sel16[i] = 0xFFFFFFFFu;
        for (int s8 = 0; s8 < 8; ++s8) {
#pragma unroll
            for (int i3 = 0; i3 < 3; ++i3) {
                const unsigned int v = akeys[(8 * tid + s8) * 3 + i3];
#pragma unroll
                for (int h = 0; h < 2; ++h) {
                    unsigned int cand = (h == 0) ? (v & 0xffffu) : (v >> 16);
                    if (cand < sel16[15]) {
#pragma unroll
                        for (int i = 0; i < 16; ++i) {
                            const unsigned int lo = umin32(sel16[i], cand);
                            cand = umax32(sel16[i], cand);
                            sel16[i] = lo;
                        }
                    }
                }
            }
        }
        const float tauf = h2f(sel16[15]) * 1.12f + 1e-9f;
        const unsigned int taub = f2h(tauf);
        const int n2 = (blockIdx.x * 32 + tid) & (Nv - 1);
        const int pq2 = n2 >> 1;
        const int hq2 = (n2 & 1) * 16;
        const uint2 qxy2 = pxy2[pq2];
        const unsigned int qzz2 = pz2[pq2];
        const unsigned int hx2 = (qxy2.x >> hq2) & 0xffffu;
        const unsigned int hy2 = (qxy2.y >> hq2) & 0xffffu;
        const unsigned int hz2 = (qzz2   >> hq2) & 0xffffu;
        qu[tid] = make_uint4(hx2 | (hx2 << 16), hy2 | (hy2 << 16),
                             hz2 | (hz2 << 16), taub);
        cnt[tid] = 0;
    }
    __syncthreads();

    // ---- Pass B: 8 packed register pairs (16 candidates) vs 32 queries ----
    uint2 cxy[8]; unsigned int czp[8];
#pragma unroll
    for (int k = 0; k < 8; ++k) {
        cxy[k] = pxy2[tid + (k << 8)];
        czp[k] = pz2[tid + (k << 8)];
    }
    for (int q2 = 0; q2 < 32; ++q2) {
        const uint4 Q = qu[q2];
        const half2v Qx = bch2(Q.x), Qy = bch2(Q.y), Qz = bch2(Q.z);
        const unsigned int taub = Q.w;
#pragma unroll
        for (int k = 0; k < 8; ++k) {
            const half2v dx = bch2(cxy[k].x) - Qx;
            const half2v dy = bch2(cxy[k].y) - Qy;
            const half2v dz = bch2(czp[k]) - Qz;
            const half2v d2 = dx * dx + dy * dy + dz * dz;
            const unsigned int bits = __builtin_bit_cast(unsigned int, d2);
            const unsigned int lo = bits & 0xffffu;
            const unsigned int hi = bits >> 16;
            const int p = tid + (k << 8);
            if (lo < taub) {
                const unsigned int slot = atomicAdd(&cnt[q2], 1u);
                if (slot < CAPv) bufs[q2 * CAPv + slot] = (unsigned short)(2 * p);
            }
            if (hi < taub) {
                const unsigned int slot = atomicAdd(&cnt[q2], 1u);
                if (slot < CAPv) bufs[q2 * CAPv + slot] = (unsigned short)(2 * p + 1);
            }
        }
    }
    __syncthreads();

    // ---- Tail: exact f64 re-rank (identical comparator to prior rounds) ---
    if (tid < 32) {
        const int q2 = blockIdx.x * 32 + tid;
        const int n2 = q2 & (Nv - 1);
        const int b2 = q2 >> 12;
        const float* pb2 = pos + (size_t)b2 * Nv * 3;
        const double qxd = (double)pb2[3 * n2];
        const double qyd = (double)pb2[3 * n2 + 1];
        const double qzd = (double)pb2[3 * n2 + 2];
        const double a2qd = qxd * qxd + qyd * qyd + qzd * qzd;
        int c = (int)cnt[tid]; if (c > CAPv) c = CAPv;
        unsigned long long sel[Kv];
#pragma unroll
        for (int i = 0; i < Kv; ++i) sel[i] = ~0ull;
        for (int t = 0; t < c; ++t) {
            const int j = bufs[tid * CAPv + t];
            const double cxd = (double)pb2[3 * j];
            const double cyd = (double)pb2[3 * j + 1];
            const double czd = (double)pb2[3 * j + 2];
            const double a2cd = cxd * cxd + cyd * cyd + czd * czd;
            const double ddot = qxd * cxd + qyd * cyd + qzd * czd;
            double dv = (a2qd + a2cd) - 2.0 * ddot;
            dv = (dv < 0.0) ? 0.0 : dv;
            if (j == n2) dv = 0.0;
            union { double d; unsigned long long u; } cv; cv.d = dv;
            const unsigned long long key = (cv.u & ~0xFFFULL) | (unsigned long long)j;
            if (key < sel[Kv - 1]) {
                unsigned long long cc = key;
#pragma unroll
                for (int i = 0; i < Kv; ++i) {
                    const unsigned long long lo = (sel[i] < cc) ? sel[i] : cc;
                    const unsigned long long hi = (sel[i] < cc) ? cc : sel[i];
                    sel[i] = lo; cc = hi;
                }
            }
        }
#pragma unroll
        for (int i = 0; i < Kv; ++i)
            idx_out[(long)q2 * Kv + i] = (int)(sel[i] & 0xFFFull);
    }
}

// ---------------- K3: gather + attention + RPE bias -> o (bf16, in-place) --
__global__ __launch_bounds__(256) void attn_core_kernel(
    unsigned short* __restrict__ qb, const unsigned short* __restrict__ kb,
    const unsigned short* __restrict__ vb, const int* __restrict__ idx,
    const float* __restrict__ pos, const float* __restrict__ W1,
    const float* __restrict__ b1, const float* __restrict__ w2sum,
    const float* __restrict__ b2sum)
{
    __shared__ float q_lds[8][Cv];
    __shared__ float lg[8][Kv];
    __shared__ float wgt[8][Kv];
    __shared__ int idx_l[8][Kv];
    __shared__ float W1l[3 * RPEv];
    __shared__ float b1l[RPEv], w2s[RPEv];
    __shared__ float posq[24];
    __shared__ float b2s_l;

    const int tid = threadIdx.x;
    const long r0 = (long)blockIdx.x * 8;   // 8 query rows per block
    const int bq = (int)(r0 >> 12);

    {
        float* ql = &q_lds[0][0];
        for (int i = tid; i < 8 * Cv; i += 256) ql[i] = bf2f(qb[r0 * Cv + i]);
    }
    if (tid < 128) ((int*)idx_l)[tid] = idx[r0 * Kv + tid];
    if (tid < 3 * RPEv) W1l[tid] = W1[tid];
    if (tid < RPEv) { b1l[tid] = b1[tid]; w2s[tid] = w2sum[tid]; }
    if (tid < 24) posq[tid] = pos[r0 * 3 + tid];
    if (tid == 0) b2s_l = *b2sum;
    __syncthreads();

    const int g = tid >> 4, l = tid & 15;   // 16 groups x 16 lanes
    for (int r = 0; r < 8; ++r) {
        const int nb = idx_l[r][g];
        const long gi = (long)bq * Nv + nb;
        const unsigned short* kr = kb + gi * Cv + l * 16;
        const float* qq = &q_lds[r][l * 16];
        const uint4 kA = *(const uint4*)kr;
        const uint4 kB = *(const uint4*)(kr + 8);
        float part = 0.f;
        part = fmaf(qq[0],  bf2f(kA.x & 0xffffu), part);
        part = fmaf(qq[1],  bf2f(kA.x >> 16),     part);
        part = fmaf(qq[2],  bf2f(kA.y & 0xffffu), part);
        part = fmaf(qq[3],  bf2f(kA.y >> 16),     part);
        part = fmaf(qq[4],  bf2f(kA.z & 0xffffu), part);
        part = fmaf(qq[5],  bf2f(kA.z >> 16),     part);
        part = fmaf(qq[6],  bf2f(kA.w & 0xffffu), part);
        part = fmaf(qq[7],  bf2f(kA.w >> 16),     part);
        part = fmaf(qq[8],  bf2f(kB.x & 0xffffu), part);
        part = fmaf(qq[9],  bf2f(kB.x >> 16),     part);
        part = fmaf(qq[10], bf2f(kB.y & 0xffffu), part);
        part = fmaf(qq[11], bf2f(kB.y >> 16),     part);
        part = fmaf(qq[12], bf2f(kB.z & 0xffffu), part);
        part = fmaf(qq[13], bf2f(kB.z >> 16),     part);
        part = fmaf(qq[14], bf2f(kB.w & 0xffffu), part);
        part = fmaf(qq[15], bf2f(kB.w >> 16),     part);
        const float rx = posq[r * 3 + 0] - pos[gi * 3 + 0];
        const float ry = posq[r * 3 + 1] - pos[gi * 3 + 1];
        const float rz = posq[r * 3 + 2] - pos[gi * 3 + 2];
#pragma unroll
        for (int u4 = 0; u4 < 4; ++u4) {
            const int u = l * 4 + u4;
            float h = fmaf(rx, W1l[u], fmaf(ry, W1l[RPEv + u], fmaf(rz, W1l[2 * RPEv + u], b1l[u])));
            h = fmaxf(h, 0.f);
            part = fmaf(h, w2s[u], part);
        }
        part += __shfl_xor(part, 8);
        part += __shfl_xor(part, 4);
        part += __shfl_xor(part, 2);
        part += __shfl_xor(part, 1);
        if (l == 0) lg[r][g] = (part + b2s_l) * 0.0625f;
    }
    __syncthreads();
    if (tid < 128) {
        const int rr = tid >> 4, gg = tid & 15;
        const float v = lg[rr][gg];
        float m = v;
        m = fmaxf(m, __shfl_xor(m, 8)); m = fmaxf(m, __shfl_xor(m, 4));
        m = fmaxf(m, __shfl_xor(m, 2)); m = fmaxf(m, __shfl_xor(m, 1));
        const float e = __expf(v - m);
        float ssum = e;
        ssum += __shfl_xor(ssum, 8); ssum += __shfl_xor(ssum, 4);
        ssum += __shfl_xor(ssum, 2); ssum += __shfl_xor(ssum, 1);
        wgt[rr][gg] = e / ssum;
    }
    __syncthreads();
    {
        const int c = tid;
        for (int r = 0; r < 8; ++r) {
            float acc = 0.f;
#pragma unroll
            for (int t = 0; t < Kv; ++t) {
                const long gi = (long)bq * Nv + idx_l[r][t];
                acc = fmaf(wgt[r][t], bf2f((unsigned)vb[gi * Cv + c]), acc);
            }
            // in-place: overwrite this block's own q rows with o (bf16)
            qb[(r0 + r) * Cv + c] = f2bf(acc);
        }
    }
}

extern "C" void kernel_launch(void* const* d_in, const int* in_sizes, int n_in,
                              void* d_out, int out_size, void* d_ws, size_t ws_size,
                              hipStream_t stream) {
    (void)in_sizes; (void)n_in; (void)out_size; (void)ws_size;
    const float* x      = (const float*)d_in[0];
    const float* pos    = (const float*)d_in[1];
    const float* Wq     = (const float*)d_in[2];
    const float* Wk     = (const float*)d_in[3];
    const float* Wv     = (const float*)d_in[4];
    const float* W1     = (const float*)d_in[5];
    const float* b1     = (const float*)d_in[6];
    const float* W2     = (const float*)d_in[7];
    const float* b2     = (const float*)d_in[8];
    const float* Wp     = (const float*)d_in[9];
    const float* bp     = (const float*)d_in[10];
    const float* gq     = (const float*)d_in[11];
    const float* betaq  = (const float*)d_in[12];
    const float* gkv    = (const float*)d_in[13];
    const float* betakv = (const float*)d_in[14];
    float* out = (float*)d_out;

    char* ws = (char*)d_ws;
    unsigned short* qb = (unsigned short*)(ws);               // 3 x 16 MiB bf16 q/k/v
    unsigned short* kb = (unsigned short*)(ws + 16777216);
    unsigned short* vb = (unsigned short*)(ws + 33554432);
    int*   idx   = (int*)  (ws + 50331648);                   // 2 MiB
    unsigned short* Bt = (unsigned short*)(ws + 52428800);    // 1024*256*2 = 512 KiB
    float* w2sum = (float*)(ws + 52953088);
    float* b2sum = (float*)(ws + 52953344);

    unsigned short* Aq  = (unsigned short*)d_out;             // d_out as scratch
    unsigned short* Akv = (unsigned short*)d_out + 8388608;

    hipLaunchKernelGGL(pre_kernel, dim3(5121), dim3(256), 0, stream,
                       x, gq, betaq, gkv, betakv, Aq, Akv,
                       Wq, Wk, Wv, Wp, Bt, W2, b2, w2sum, b2sum);
    hipLaunchKernelGGL(gemm_qkv_kernel, dim3(256, 6), dim3(256), 0, stream,
                       Aq, Akv, Bt, qb, kb, vb);
    hipLaunchKernelGGL(knn_kernel, dim3(1024), dim3(256), 0, stream, pos, idx);
    hipLaunchKernelGGL(attn_core_kernel, dim3(4096), dim3(256), 0, stream,
                       qb, kb, vb, idx, pos, W1, b1, w2sum, b2sum);
    // o (bf16, in qb) @ Wp^T + bp -> f32 out
    hipLaunchKernelGGL(gemm_proj_kernel, dim3(256, 2), dim3(256), 0, stream,
                       qb, Bt + 768 * 256, bp, out);
}

// Round 9
// 222.031 us; speedup vs baseline: 1.0007x; 1.0007x over previous
//
#include <hip/hip_runtime.h>
#include <hip/hip_bf16.h>
#include <stdint.h>

#define Bv 8
#define Nv 4096
#define Cv 256
#define Kv 16
#define RPEv 64
#define CAPv 160

typedef short bf16x8 __attribute__((ext_vector_type(8)));
typedef float f32x4 __attribute__((ext_vector_type(4)));
typedef _Float16 half2v __attribute__((ext_vector_type(2)));
typedef unsigned short u16x2 __attribute__((ext_vector_type(2)));

static __device__ __forceinline__ float bf2f(unsigned int u16) {
    union { unsigned int i; float f; } v; v.i = u16 << 16; return v.f;
}
static __device__ __forceinline__ unsigned short f2bf(float f) {
    union { float f; unsigned int i; } v; v.f = f;
    unsigned int x = v.i;
    return (unsigned short)((x + 0x7fffu + ((x >> 16) & 1u)) >> 16);
}
static __device__ __forceinline__ unsigned int umin32(unsigned int a, unsigned int b) { return a < b ? a : b; }
static __device__ __forceinline__ unsigned int umax32(unsigned int a, unsigned int b) { return a > b ? a : b; }
static __device__ __forceinline__ unsigned short f2h(float f) {
    _Float16 h = (_Float16)f; return __builtin_bit_cast(unsigned short, h);
}
static __device__ __forceinline__ float h2f(unsigned int u) {
    _Float16 h = __builtin_bit_cast(_Float16, (unsigned short)(u & 0xffffu)); return (float)h;
}
static __device__ __forceinline__ half2v bch2(unsigned int u) { return __builtin_bit_cast(half2v, u); }
static __device__ __forceinline__ unsigned int bcu32(u16x2 v) { return __builtin_bit_cast(unsigned int, v); }

// ---------------- K0: fused preamble ---------------------------------------
// blocks 0-4095: dual LayerNorm + bf16 cast; 4096-5119: weight transpose;
// 5120: w2sum/b2sum; 5121-5128: fp16 position prepack (per batch).
__global__ __launch_bounds__(256) void pre_kernel(
    const float* __restrict__ x,
    const float* __restrict__ gq, const float* __restrict__ bq,
    const float* __restrict__ gkv, const float* __restrict__ bkv,
    unsigned short* __restrict__ Aq, unsigned short* __restrict__ Akv,
    const float* __restrict__ Wq, const float* __restrict__ Wk,
    const float* __restrict__ Wv, const float* __restrict__ Wp,
    unsigned short* __restrict__ Bt,
    const float* __restrict__ W2, const float* __restrict__ b2,
    float* __restrict__ w2sum, float* __restrict__ b2sum,
    const float* __restrict__ pos, char* __restrict__ ppos)
{
    const int bid = blockIdx.x;
    const int tid = threadIdx.x;
    if (bid < 4096) {
        // ---- dual LayerNorm + bf16 cast ----
        const long r0 = (long)bid * 8;
        const int row = tid >> 5;
        const int c0 = (tid & 31) * 8;
        const float* xr = x + (r0 + row) * Cv + c0;
        float xv[8];
        *(float4*)&xv[0] = *(const float4*)xr;
        *(float4*)&xv[4] = *(const float4*)(xr + 4);
        float s = 0.f, s2 = 0.f;
#pragma unroll
        for (int i = 0; i < 8; ++i) { s += xv[i]; s2 = fmaf(xv[i], xv[i], s2); }
#pragma unroll
        for (int m = 16; m >= 1; m >>= 1) { s += __shfl_xor(s, m); s2 += __shfl_xor(s2, m); }
        const float mean = s * (1.f / Cv);
        const float var = fmaf(-mean, mean, s2 * (1.f / Cv));
        const float rs = rsqrtf(fmaxf(var, 0.f) + 1e-5f);
        unsigned int pq[4], pk[4];
#pragma unroll
        for (int i = 0; i < 4; ++i) {
            const int c = c0 + 2 * i;
            const float h0 = (xv[2 * i] - mean) * rs;
            const float h1 = (xv[2 * i + 1] - mean) * rs;
            const unsigned int q0 = f2bf(fmaf(h0, gq[c], bq[c]));
            const unsigned int q1 = f2bf(fmaf(h1, gq[c + 1], bq[c + 1]));
            const unsigned int k0 = f2bf(fmaf(h0, gkv[c], bkv[c]));
            const unsigned int k1 = f2bf(fmaf(h1, gkv[c + 1], bkv[c + 1]));
            pq[i] = q0 | (q1 << 16);
            pk[i] = k0 | (k1 << 16);
        }
        const long off = (r0 + row) * Cv + c0;
        *(uint4*)&Aq[off]  = make_uint4(pq[0], pq[1], pq[2], pq[3]);
        *(uint4*)&Akv[off] = make_uint4(pk[0], pk[1], pk[2], pk[3]);
    } else if (bid < 5120) {
        // ---- weight transpose-cast: Bt[1024][256] ----
        const int r = bid - 4096;
        const float* W = (r < 256) ? Wq : (r < 512) ? Wk : (r < 768) ? Wv : Wp;
        const int n = r & 255;
        Bt[r * 256 + tid] = f2bf(W[tid * 256 + n]);
    } else if (bid == 5120) {
        // ---- w2sum / b2sum ----
        if (tid < RPEv) {
            float s = 0.f;
            for (int c = 0; c < Cv; ++c) s += W2[tid * Cv + c];
            w2sum[tid] = s;
        }
        if (tid == 0) {
            float s = 0.f;
            for (int c = 0; c < Cv; ++c) s += b2[c];
            *b2sum = s;
        }
    } else {
        // ---- fp16 prepack: batch b, 2048 pairs ----
        const int b = bid - 5121;
        const float* pb = pos + (size_t)b * Nv * 3;
        uint2* oxy = (uint2*)(ppos + (size_t)b * 24576);
        unsigned int* oz = (unsigned int*)(ppos + (size_t)b * 24576 + 16384);
        for (int i = tid; i < Nv / 2; i += 256) {
            const float* pp = pb + 6 * i;
            const float2 u0 = *(const float2*)pp;
            const float2 u1 = *(const float2*)(pp + 2);
            const float2 u2 = *(const float2*)(pp + 4);
            const unsigned int x0 = f2h(u0.x), y0 = f2h(u0.y), z0 = f2h(u1.x);
            const unsigned int x1 = f2h(u1.y), y1 = f2h(u2.x), z1 = f2h(u2.y);
            oxy[i] = make_uint2(x0 | (x1 << 16), y0 | (y1 << 16));
            oz[i] = z0 | (z1 << 16);
        }
    }
}

// ---------------- K1b: bf16 MFMA GEMM  C[32768 x 768] = A @ W (bf16 out) ---
__global__ __launch_bounds__(256) void gemm_qkv_kernel(
    const unsigned short* __restrict__ Aq, const unsigned short* __restrict__ Akv,
    const unsigned short* __restrict__ Bt,
    unsigned short* __restrict__ qo, unsigned short* __restrict__ ko,
    unsigned short* __restrict__ vo)
{
    __shared__ unsigned short Albs[2][128 * 64];
    __shared__ unsigned short Blbs[2][128 * 64];

    const int tid = threadIdx.x;
    const int rt = blockIdx.x;          // row tile: 256
    const int ct = blockIdx.y;          // col tile: 6
    const unsigned short* A = (ct < 2) ? Aq : Akv;
    const int mat = ct >> 1;
    unsigned short* outp = (mat == 0) ? qo : (mat == 1) ? ko : vo;
    const int colInMat = (ct & 1) * 128;

    const int wid = tid >> 6, l = tid & 63;
    const int wr = wid >> 1, wc = wid & 1;

    int srow[4], scol8[4];
#pragma unroll
    for (int it = 0; it < 4; ++it) {
        const int chunk = it * 256 + tid;
        srow[it] = chunk >> 3;
        scol8[it] = ((chunk & 7) ^ (srow[it] & 7)) * 8;
    }

#define STAGE(buf, ks)                                                                  \
    {                                                                                   \
        _Pragma("unroll")                                                               \
        for (int it = 0; it < 4; ++it) {                                                \
            const unsigned short* ga = A + ((size_t)(rt * 128 + srow[it])) * 256        \
                                         + (ks) * 64 + scol8[it];                       \
            const unsigned short* gb = Bt + ((size_t)(ct * 128 + srow[it])) * 256       \
                                          + (ks) * 64 + scol8[it];                      \
            __builtin_amdgcn_global_load_lds(                                           \
                (const __attribute__((address_space(1))) unsigned int*)(const void*)ga, \
                (__attribute__((address_space(3))) unsigned int*)(void*)                \
                    ((char*)&Albs[buf][0] + (it * 256 + tid) * 16), 16, 0, 0);          \
            __builtin_amdgcn_global_load_lds(                                           \
                (const __attribute__((address_space(1))) unsigned int*)(const void*)gb, \
                (__attribute__((address_space(3))) unsigned int*)(void*)                \
                    ((char*)&Blbs[buf][0] + (it * 256 + tid) * 16), 16, 0, 0);          \
        }                                                                               \
    }

    f32x4 acc[4][4];
#pragma unroll
    for (int m = 0; m < 4; ++m)
#pragma unroll
        for (int n = 0; n < 4; ++n) acc[m][n] = (f32x4){0.f, 0.f, 0.f, 0.f};

    STAGE(0, 0);
    __syncthreads();

    for (int ks = 0; ks < 4; ++ks) {
        const int cur = ks & 1;
        if (ks < 3) STAGE(cur ^ 1, ks + 1);
#pragma unroll
        for (int kk = 0; kk < 2; ++kk) {
            bf16x8 a[4], b[4];
#pragma unroll
            for (int m = 0; m < 4; ++m) {
                const int row = wr * 64 + m * 16 + (l & 15);
                const int byte = row * 128 + ((((kk * 4 + (l >> 4)) * 16)) ^ ((row & 7) << 4));
                a[m] = *(const bf16x8*)((const char*)&Albs[cur][0] + byte);
            }
#pragma unroll
            for (int n = 0; n < 4; ++n) {
                const int row = wc * 64 + n * 16 + (l & 15);
                const int byte = row * 128 + ((((kk * 4 + (l >> 4)) * 16)) ^ ((row & 7) << 4));
                b[n] = *(const bf16x8*)((const char*)&Blbs[cur][0] + byte);
            }
#pragma unroll
            for (int m = 0; m < 4; ++m)
#pragma unroll
                for (int n = 0; n < 4; ++n)
                    acc[m][n] = __builtin_amdgcn_mfma_f32_16x16x32_bf16(a[m], b[n], acc[m][n], 0, 0, 0);
        }
        __syncthreads();
    }

#pragma unroll
    for (int m = 0; m < 4; ++m) {
#pragma unroll
        for (int n = 0; n < 4; ++n) {
#pragma unroll
            for (int j = 0; j < 4; ++j) {
                const int row = rt * 128 + wr * 64 + m * 16 + (l >> 4) * 4 + j;
                const int col = colInMat + wc * 64 + n * 16 + (l & 15);
                outp[(size_t)row * 256 + col] = f2bf(acc[m][n][j]);
            }
        }
    }
#undef STAGE
}

// ---------------- K4: proj GEMM  out[32768 x 256] = o @ Wp^T + bp (f32) ----
__global__ __launch_bounds__(256) void gemm_proj_kernel(
    const unsigned short* __restrict__ Ab, const unsigned short* __restrict__ Btp,
    const float* __restrict__ bp, float* __restrict__ out)
{
    __shared__ unsigned short Albs[2][128 * 64];
    __shared__ unsigned short Blbs[2][128 * 64];

    const int tid = threadIdx.x;
    const int rt = blockIdx.x;          // 256
    const int ct = blockIdx.y;          // 2

    const int wid = tid >> 6, l = tid & 63;
    const int wr = wid >> 1, wc = wid & 1;

    int srow[4], scol8[4];
#pragma unroll
    for (int it = 0; it < 4; ++it) {
        const int chunk = it * 256 + tid;
        srow[it] = chunk >> 3;
        scol8[it] = ((chunk & 7) ^ (srow[it] & 7)) * 8;
    }

#define STAGE(buf, ks)                                                                  \
    {                                                                                   \
        _Pragma("unroll")                                                               \
        for (int it = 0; it < 4; ++it) {                                                \
            const unsigned short* ga = Ab + ((size_t)(rt * 128 + srow[it])) * 256       \
                                          + (ks) * 64 + scol8[it];                      \
            const unsigned short* gb = Btp + ((size_t)(ct * 128 + srow[it])) * 256      \
                                           + (ks) * 64 + scol8[it];                     \
            __builtin_amdgcn_global_load_lds(                                           \
                (const __attribute__((address_space(1))) unsigned int*)(const void*)ga, \
                (__attribute__((address_space(3))) unsigned int*)(void*)                \
                    ((char*)&Albs[buf][0] + (it * 256 + tid) * 16), 16, 0, 0);          \
            __builtin_amdgcn_global_load_lds(                                           \
                (const __attribute__((address_space(1))) unsigned int*)(const void*)gb, \
                (__attribute__((address_space(3))) unsigned int*)(void*)                \
                    ((char*)&Blbs[buf][0] + (it * 256 + tid) * 16), 16, 0, 0);          \
        }                                                                               \
    }

    f32x4 acc[4][4];
#pragma unroll
    for (int m = 0; m < 4; ++m)
#pragma unroll
        for (int n = 0; n < 4; ++n) acc[m][n] = (f32x4){0.f, 0.f, 0.f, 0.f};

    STAGE(0, 0);
    __syncthreads();

    for (int ks = 0; ks < 4; ++ks) {
        const int cur = ks & 1;
        if (ks < 3) STAGE(cur ^ 1, ks + 1);
#pragma unroll
        for (int kk = 0; kk < 2; ++kk) {
            bf16x8 a[4], b[4];
#pragma unroll
            for (int m = 0; m < 4; ++m) {
                const int row = wr * 64 + m * 16 + (l & 15);
                const int byte = row * 128 + ((((kk * 4 + (l >> 4)) * 16)) ^ ((row & 7) << 4));
                a[m] = *(const bf16x8*)((const char*)&Albs[cur][0] + byte);
            }
#pragma unroll
            for (int n = 0; n < 4; ++n) {
                const int row = wc * 64 + n * 16 + (l & 15);
                const int byte = row * 128 + ((((kk * 4 + (l >> 4)) * 16)) ^ ((row & 7) << 4));
                b[n] = *(const bf16x8*)((const char*)&Blbs[cur][0] + byte);
            }
#pragma unroll
            for (int m = 0; m < 4; ++m)
#pragma unroll
                for (int n = 0; n < 4; ++n)
                    acc[m][n] = __builtin_amdgcn_mfma_f32_16x16x32_bf16(a[m], b[n], acc[m][n], 0, 0, 0);
        }
        __syncthreads();
    }

#pragma unroll
    for (int n = 0; n < 4; ++n) {
        const int col = ct * 128 + wc * 64 + n * 16 + (l & 15);
        const float bpv = bp[col];
#pragma unroll
        for (int m = 0; m < 4; ++m) {
#pragma unroll
            for (int j = 0; j < 4; ++j) {
                const int row = rt * 128 + wr * 64 + m * 16 + (l >> 4) * 4 + j;
                out[(size_t)row * 256 + col] = acc[m][n][j] + bpv;
            }
        }
    }
#undef STAGE
}

// ---------------- K2: kNN v8 — R7 chain + half-sample + gload staging ------
// Stage: prepacked fp16 via global_load_lds (6x16B/thread, linear dest).
// Pass A: 8 thr/query, pairs p=8t+s for t<128 (first half; subset => valid
//         tau bound), single branchless packed chain-3 -> 48-union -> tau.
// Pass B: full scan, 8 packed reg-pairs/thread vs 32 queries, LDS append.
// Tail: exact f64 re-rank of survivors (bit-identical comparator).
__global__ __launch_bounds__(256) void knn_kernel(
    const float* __restrict__ pos, const char* __restrict__ ppos,
    int* __restrict__ idx_out)
{
    __shared__ char Pbuf[24576];                 // pxy2[2048] then pz2[2048]
    __shared__ uint4 qu[32];                     // qx_pk, qy_pk, qz_pk, tau_u16
    __shared__ unsigned int akeys[256 * 3];      // 3 KB pass-A packed chains
    __shared__ unsigned int cnt[32];
    __shared__ unsigned short bufs[32 * CAPv];   // 10 KB survivor indices

    const uint2* pxy2 = (const uint2*)Pbuf;
    const unsigned int* pz2 = (const unsigned int*)(Pbuf + 16384);

    const int tid = threadIdx.x;
    const int ql = tid >> 3;                 // 0..31 query within block
    const int s  = tid & 7;                  // segment 0..7
    const int q  = blockIdx.x * 32 + ql;
    const int b  = q >> 12;
    const int n  = q & (Nv - 1);

    {
        const char* src = ppos + (size_t)b * 24576;
#pragma unroll
        for (int it = 0; it < 6; ++it) {
            const int off = (it * 256 + tid) * 16;
            __builtin_amdgcn_global_load_lds(
                (const __attribute__((address_space(1))) unsigned int*)(const void*)(src + off),
                (__attribute__((address_space(3))) unsigned int*)(void*)(Pbuf + off),
                16, 0, 0);
        }
    }
    __syncthreads();

    // query packed regs (broadcast fp16 into both halves)
    const int pq = n >> 1;
    const int hq = (n & 1) * 16;
    const uint2 qxy = pxy2[pq];
    const unsigned int qzz = pz2[pq];
    const unsigned int hx = (qxy.x >> hq) & 0xffffu;
    const unsigned int hy = (qxy.y >> hq) & 0xffffu;
    const unsigned int hz = (qzz   >> hq) & 0xffffu;
    const half2v qxp = bch2(hx | (hx << 16));
    const half2v qyp = bch2(hy | (hy << 16));
    const half2v qzp = bch2(hz | (hz << 16));

    // ---- Pass A: half sample (pairs 0..1023), branchless packed chain-3 ----
    u16x2 ch0 = {0x7c00, 0x7c00}, ch1 = ch0, ch2 = ch0;   // +inf fp16
    for (int t = 0; t < 128; ++t) {
        const int p = 8 * t + s;
        const uint2 xy = pxy2[p];
        const unsigned int zz = pz2[p];
        const half2v dx = bch2(xy.x) - qxp;
        const half2v dy = bch2(xy.y) - qyp;
        const half2v dz = bch2(zz) - qzp;
        const half2v d2 = dx * dx + dy * dy + dz * dz;
        const u16x2 k = __builtin_bit_cast(u16x2, d2);
        const u16x2 mn0 = __builtin_elementwise_min(ch0, k);
        const u16x2 mx0 = __builtin_elementwise_max(ch0, k);
        ch0 = mn0;
        const u16x2 mn1 = __builtin_elementwise_min(ch1, mx0);
        const u16x2 mx1 = __builtin_elementwise_max(ch1, mx0);
        ch1 = mn1;
        ch2 = __builtin_elementwise_min(ch2, mx1);
    }
    akeys[tid * 3 + 0] = bcu32(ch0);
    akeys[tid * 3 + 1] = bcu32(ch1);
    akeys[tid * 3 + 2] = bcu32(ch2);
    __syncthreads();

    // ---- merge: 16th smallest of the 48-union -> tau ----
    if (tid < 32) {
        unsigned int sel16[16];
#pragma unroll
        for (int i = 0; i < 16; ++i) sel16[i] = 0xFFFFFFFFu;
        for (int s8 = 0; s8 < 8; ++s8) {
#pragma unroll
            for (int i3 = 0; i3 < 3; ++i3) {
                const unsigned int v = akeys[(8 * tid + s8) * 3 + i3];
#pragma unroll
                for (int h = 0; h < 2; ++h) {
                    unsigned int cand = (h == 0) ? (v & 0xffffu) : (v >> 16);
                    if (cand < sel16[15]) {
#pragma unroll
                        for (int i = 0; i < 16; ++i) {
                            const unsigned int lo = umin32(sel16[i], cand);
                            cand = umax32(sel16[i], cand);
                            sel16[i] = lo;
                        }
                    }
                }
            }
        }
        const float tauf = h2f(sel16[15]) * 1.12f + 1e-9f;
        const unsigned int taub = f2h(tauf);
        const int n2 = (blockIdx.x * 32 + tid) & (Nv - 1);
        const int pq2 = n2 >> 1;
        const int hq2 = (n2 & 1) * 16;
        const uint2 qxy2 = pxy2[pq2];
        const unsigned int qzz2 = pz2[pq2];
        const unsigned int hx2 = (qxy2.x >> hq2) & 0xffffu;
        const unsigned int hy2 = (qxy2.y >> hq2) & 0xffffu;
        const unsigned int hz2 = (qzz2   >> hq2) & 0xffffu;
        qu[tid] = make_uint4(hx2 | (hx2 << 16), hy2 | (hy2 << 16),
                             hz2 | (hz2 << 16), taub);
        cnt[tid] = 0;
    }
    __syncthreads();

    // ---- Pass B: 8 packed register pairs (16 candidates) vs 32 queries ----
    uint2 cxy[8]; unsigned int czp[8];
#pragma unroll
    for (int k = 0; k < 8; ++k) {
        cxy[k] = pxy2[tid + (k << 8)];
        czp[k] = pz2[tid + (k << 8)];
    }
    for (int q2 = 0; q2 < 32; ++q2) {
        const uint4 Q = qu[q2];
        const half2v Qx = bch2(Q.x), Qy = bch2(Q.y), Qz = bch2(Q.z);
        const unsigned int taub = Q.w;
#pragma unroll
        for (int k = 0; k < 8; ++k) {
            const half2v dx = bch2(cxy[k].x) - Qx;
            const half2v dy = bch2(cxy[k].y) - Qy;
            const half2v dz = bch2(czp[k]) - Qz;
            const half2v d2 = dx * dx + dy * dy + dz * dz;
            const unsigned int bits = __builtin_bit_cast(unsigned int, d2);
            const unsigned int lo = bits & 0xffffu;
            const unsigned int hi = bits >> 16;
            const int p = tid + (k << 8);
            if (lo < taub) {
                const unsigned int slot = atomicAdd(&cnt[q2], 1u);
                if (slot < CAPv) bufs[q2 * CAPv + slot] = (unsigned short)(2 * p);
            }
            if (hi < taub) {
                const unsigned int slot = atomicAdd(&cnt[q2], 1u);
                if (slot < CAPv) bufs[q2 * CAPv + slot] = (unsigned short)(2 * p + 1);
            }
        }
    }
    __syncthreads();

    // ---- Tail: exact f64 re-rank (identical comparator to prior rounds) ---
    if (tid < 32) {
        const int q2 = blockIdx.x * 32 + tid;
        const int n2 = q2 & (Nv - 1);
        const int b2 = q2 >> 12;
        const float* pb2 = pos + (size_t)b2 * Nv * 3;
        const double qxd = (double)pb2[3 * n2];
        const double qyd = (double)pb2[3 * n2 + 1];
        const double qzd = (double)pb2[3 * n2 + 2];
        const double a2qd = qxd * qxd + qyd * qyd + qzd * qzd;
        int c = (int)cnt[tid]; if (c > CAPv) c = CAPv;
        unsigned long long sel[Kv];
#pragma unroll
        for (int i = 0; i < Kv; ++i) sel[i] = ~0ull;
        for (int t = 0; t < c; ++t) {
            const int j = bufs[tid * CAPv + t];
            const double cxd = (double)pb2[3 * j];
            const double cyd = (double)pb2[3 * j + 1];
            const double czd = (double)pb2[3 * j + 2];
            const double a2cd = cxd * cxd + cyd * cyd + czd * czd;
            const double ddot = qxd * cxd + qyd * cyd + qzd * czd;
            double dv = (a2qd + a2cd) - 2.0 * ddot;
            dv = (dv < 0.0) ? 0.0 : dv;
            if (j == n2) dv = 0.0;
            union { double d; unsigned long long u; } cv; cv.d = dv;
            const unsigned long long key = (cv.u & ~0xFFFULL) | (unsigned long long)j;
            if (key < sel[Kv - 1]) {
                unsigned long long cc = key;
#pragma unroll
                for (int i = 0; i < Kv; ++i) {
                    const unsigned long long lo = (sel[i] < cc) ? sel[i] : cc;
                    const unsigned long long hi = (sel[i] < cc) ? cc : sel[i];
                    sel[i] = lo; cc = hi;
                }
            }
        }
#pragma unroll
        for (int i = 0; i < Kv; ++i)
            idx_out[(long)q2 * Kv + i] = (int)(sel[i] & 0xFFFull);
    }
}

// ---------------- K3: gather + attention + RPE bias -> o (bf16, in-place) --
__global__ __launch_bounds__(256) void attn_core_kernel(
    unsigned short* __restrict__ qb, const unsigned short* __restrict__ kb,
    const unsigned short* __restrict__ vb, const int* __restrict__ idx,
    const float* __restrict__ pos, const float* __restrict__ W1,
    const float* __restrict__ b1, const float* __restrict__ w2sum,
    const float* __restrict__ b2sum)
{
    __shared__ float q_lds[8][Cv];
    __shared__ float lg[8][Kv];
    __shared__ float wgt[8][Kv];
    __shared__ int idx_l[8][Kv];
    __shared__ float W1l[3 * RPEv];
    __shared__ float b1l[RPEv], w2s[RPEv];
    __shared__ float posq[24];
    __shared__ float b2s_l;

    const int tid = threadIdx.x;
    const long r0 = (long)blockIdx.x * 8;   // 8 query rows per block
    const int bq = (int)(r0 >> 12);

    {
        float* ql = &q_lds[0][0];
        for (int i = tid; i < 8 * Cv; i += 256) ql[i] = bf2f(qb[r0 * Cv + i]);
    }
    if (tid < 128) ((int*)idx_l)[tid] = idx[r0 * Kv + tid];
    if (tid < 3 * RPEv) W1l[tid] = W1[tid];
    if (tid < RPEv) { b1l[tid] = b1[tid]; w2s[tid] = w2sum[tid]; }
    if (tid < 24) posq[tid] = pos[r0 * 3 + tid];
    if (tid == 0) b2s_l = *b2sum;
    __syncthreads();

    const int g = tid >> 4, l = tid & 15;   // 16 groups x 16 lanes
    for (int r = 0; r < 8; ++r) {
        const int nb = idx_l[r][g];
        const long gi = (long)bq * Nv + nb;
        const unsigned short* kr = kb + gi * Cv + l * 16;
        const float* qq = &q_lds[r][l * 16];
        const uint4 kA = *(const uint4*)kr;
        const uint4 kB = *(const uint4*)(kr + 8);
        float part = 0.f;
        part = fmaf(qq[0],  bf2f(kA.x & 0xffffu), part);
        part = fmaf(qq[1],  bf2f(kA.x >> 16),     part);
        part = fmaf(qq[2],  bf2f(kA.y & 0xffffu), part);
        part = fmaf(qq[3],  bf2f(kA.y >> 16),     part);
        part = fmaf(qq[4],  bf2f(kA.z & 0xffffu), part);
        part = fmaf(qq[5],  bf2f(kA.z >> 16),     part);
        part = fmaf(qq[6],  bf2f(kA.w & 0xffffu), part);
        part = fmaf(qq[7],  bf2f(kA.w >> 16),     part);
        part = fmaf(qq[8],  bf2f(kB.x & 0xffffu), part);
        part = fmaf(qq[9],  bf2f(kB.x >> 16),     part);
        part = fmaf(qq[10], bf2f(kB.y & 0xffffu), part);
        part = fmaf(qq[11], bf2f(kB.y >> 16),     part);
        part = fmaf(qq[12], bf2f(kB.z & 0xffffu), part);
        part = fmaf(qq[13], bf2f(kB.z >> 16),     part);
        part = fmaf(qq[14], bf2f(kB.w & 0xffffu), part);
        part = fmaf(qq[15], bf2f(kB.w >> 16),     part);
        const float rx = posq[r * 3 + 0] - pos[gi * 3 + 0];
        const float ry = posq[r * 3 + 1] - pos[gi * 3 + 1];
        const float rz = posq[r * 3 + 2] - pos[gi * 3 + 2];
#pragma unroll
        for (int u4 = 0; u4 < 4; ++u4) {
            const int u = l * 4 + u4;
            float h = fmaf(rx, W1l[u], fmaf(ry, W1l[RPEv + u], fmaf(rz, W1l[2 * RPEv + u], b1l[u])));
            h = fmaxf(h, 0.f);
            part = fmaf(h, w2s[u], part);
        }
        part += __shfl_xor(part, 8);
        part += __shfl_xor(part, 4);
        part += __shfl_xor(part, 2);
        part += __shfl_xor(part, 1);
        if (l == 0) lg[r][g] = (part + b2s_l) * 0.0625f;
    }
    __syncthreads();
    if (tid < 128) {
        const int rr = tid >> 4, gg = tid & 15;
        const float v = lg[rr][gg];
        float m = v;
        m = fmaxf(m, __shfl_xor(m, 8)); m = fmaxf(m, __shfl_xor(m, 4));
        m = fmaxf(m, __shfl_xor(m, 2)); m = fmaxf(m, __shfl_xor(m, 1));
        const float e = __expf(v - m);
        float ssum = e;
        ssum += __shfl_xor(ssum, 8); ssum += __shfl_xor(ssum, 4);
        ssum += __shfl_xor(ssum, 2); ssum += __shfl_xor(ssum, 1);
        wgt[rr][gg] = e / ssum;
    }
    __syncthreads();
    {
        const int c = tid;
        for (int r = 0; r < 8; ++r) {
            float acc = 0.f;
#pragma unroll
            for (int t = 0; t < Kv; ++t) {
                const long gi = (long)bq * Nv + idx_l[r][t];
                acc = fmaf(wgt[r][t], bf2f((unsigned)vb[gi * Cv + c]), acc);
            }
            // in-place: overwrite this block's own q rows with o (bf16)
            qb[(r0 + r) * Cv + c] = f2bf(acc);
        }
    }
}

extern "C" void kernel_launch(void* const* d_in, const int* in_sizes, int n_in,
                              void* d_out, int out_size, void* d_ws, size_t ws_size,
                              hipStream_t stream) {
    (void)in_sizes; (void)n_in; (void)out_size; (void)ws_size;
    const float* x      = (const float*)d_in[0];
    const float* pos    = (const float*)d_in[1];
    const float* Wq     = (const float*)d_in[2];
    const float* Wk     = (const float*)d_in[3];
    const float* Wv     = (const float*)d_in[4];
    const float* W1     = (const float*)d_in[5];
    const float* b1     = (const float*)d_in[6];
    const float* W2     = (const float*)d_in[7];
    const float* b2     = (const float*)d_in[8];
    const float* Wp     = (const float*)d_in[9];
    const float* bp     = (const float*)d_in[10];
    const float* gq     = (const float*)d_in[11];
    const float* betaq  = (const float*)d_in[12];
    const float* gkv    = (const float*)d_in[13];
    const float* betakv = (const float*)d_in[14];
    float* out = (float*)d_out;

    char* ws = (char*)d_ws;
    unsigned short* qb = (unsigned short*)(ws);               // 3 x 16 MiB bf16 q/k/v
    unsigned short* kb = (unsigned short*)(ws + 16777216);
    unsigned short* vb = (unsigned short*)(ws + 33554432);
    int*   idx   = (int*)  (ws + 50331648);                   // 2 MiB
    unsigned short* Bt = (unsigned short*)(ws + 52428800);    // 512 KiB
    float* w2sum = (float*)(ws + 52953088);
    float* b2sum = (float*)(ws + 52953344);
    char*  ppos  = ws + 52953600;                             // 8 x 24576 B fp16 packed

    unsigned short* Aq  = (unsigned short*)d_out;             // d_out as scratch
    unsigned short* Akv = (unsigned short*)d_out + 8388608;

    hipLaunchKernelGGL(pre_kernel, dim3(5129), dim3(256), 0, stream,
                       x, gq, betaq, gkv, betakv, Aq, Akv,
                       Wq, Wk, Wv, Wp, Bt, W2, b2, w2sum, b2sum, pos, ppos);
    hipLaunchKernelGGL(gemm_qkv_kernel, dim3(256, 6), dim3(256), 0, stream,
                       Aq, Akv, Bt, qb, kb, vb);
    hipLaunchKernelGGL(knn_kernel, dim3(1024), dim3(256), 0, stream, pos, ppos, idx);
    hipLaunchKernelGGL(attn_core_kernel, dim3(4096), dim3(256), 0, stream,
                       qb, kb, vb, idx, pos, W1, b1, w2sum, b2sum);
    // o (bf16, in qb) @ Wp^T + bp -> f32 out
    hipLaunchKernelGGL(gemm_proj_kernel, dim3(256, 2), dim3(256), 0, stream,
                       qb, Bt + 768 * 256, bp, out);
}